// Round 6
// baseline (132.500 us; speedup 1.0000x reference)
//
#include <hip/hip_runtime.h>
#include <hip/hip_bf16.h>

#define BATCH  4096
#define NUM_GO 30000
#define DIM    128

#define BM      256       // rows per block: 8 waves x 2 row-tiles x 16
#define THREADS 512
#define CPS     4         // 64-GO chunks per block (1024B-per-row mask visits)
constexpr int NCHUNKS = (NUM_GO + 63) / 64;          // 469 (last: 3 subtiles)
constexpr int NSEG    = (NCHUNKS + CPS - 1) / CPS;   // 118 (last seg: 1 chunk)
constexpr int NGO_PAD = NCHUNKS * 64;                // 30016
constexpr int NFRAGP  = (NGO_PAD / 16) * 4 * 64;     // 480256 16B fragments
#define CHUNK_BYTES 16384                             // 64 go x 128 dim x 2B
#define NBLK    ((BATCH / BM) * NSEG)                 // 1888 = 16 x 118

typedef __bf16 bf16x8 __attribute__((ext_vector_type(8)));
typedef float  f32x4  __attribute__((ext_vector_type(4)));
typedef int    i32x4  __attribute__((ext_vector_type(4)));

__device__ inline short f2bf(float x) {
    __hip_bfloat16 b = __float2bfloat16(x);
    return __builtin_bit_cast(short, b);
}

__device__ __forceinline__ void gload_lds16(const void* g, void* l) {
    __builtin_amdgcn_global_load_lds(
        (const __attribute__((address_space(1))) void*)g,
        (__attribute__((address_space(3))) void*)l, 16, 0, 0);
}

// P: f32 -> bf16 linear
__global__ __launch_bounds__(256) void cvt_bf16(const float* __restrict__ src,
                                                short* __restrict__ dst, int n4) {
    int i = blockIdx.x * blockDim.x + threadIdx.x;
    if (i >= n4) return;
    float4 v = ((const float4*)src)[i];
    short4 o = make_short4(f2bf(v.x), f2bf(v.y), f2bf(v.z), f2bf(v.w));
    ((short4*)dst)[i] = o;
}

// F: f32 -> bf16 packed in MFMA-fragment order, zero-padded to NGO_PAD rows.
__global__ __launch_bounds__(256) void cvt_F_packed(const float* __restrict__ F,
                                                    short* __restrict__ Fp) {
    int t = blockIdx.x * 256 + threadIdx.x;
    if (t >= NFRAGP) return;
    int lcol = t & 15, lrow = (t >> 4) & 3, ks = (t >> 6) & 3, g = t >> 8;
    int row = g * 16 + lcol;
    union { short s[8]; int4 v; } u;
    if (row < NUM_GO) {
        const float* src = F + (size_t)row * DIM + ks * 32 + lrow * 8;
#pragma unroll
        for (int i = 0; i < 8; ++i) u.s[i] = f2bf(src[i]);
    } else {
        u.v = make_int4(0, 0, 0, 0);
    }
    *(int4*)(Fp + (size_t)t * 8) = u.v;
}

// One 64-go chunk; F from LDS, mask bits from a register u64 per row-tile.
// Swapped MFMA mfma(F,P): lane (lcol,lrow), reg i holds
// logits[r = r0 + lcol][go = chunk*64 + t*16 + lrow*4 + i]  -> bit index
// within the chunk's u64 word is exactly t*16 + lrow*4 + i.
template<int NT>
__device__ __forceinline__ void chunk_compute(
    const short* __restrict__ flds,
    unsigned long long wv0, unsigned long long wv1,
    const bf16x8 a0[4], const bf16x8 a1[4],
    int lane, int lrow, float s2,
    float& sum0, float& pos0, float& sum1, float& pos1)
{
#pragma unroll
    for (int t = 0; t < NT; ++t) {
        bf16x8 f[4];
#pragma unroll
        for (int ks = 0; ks < 4; ++ks)
            f[ks] = *(const bf16x8*)(flds + (t * 256 + ks * 64 + lane) * 8);
        unsigned b0 = (unsigned)(wv0 >> (t * 16 + lrow * 4)) & 0xFu;
        unsigned b1 = (unsigned)(wv1 >> (t * 16 + lrow * 4)) & 0xFu;
        f32x4 acc0 = {0.f, 0.f, 0.f, 0.f};
        f32x4 acc1 = {0.f, 0.f, 0.f, 0.f};
#pragma unroll
        for (int ks = 0; ks < 4; ++ks) {
            acc0 = __builtin_amdgcn_mfma_f32_16x16x32_bf16(f[ks], a0[ks], acc0, 0, 0, 0);
            acc1 = __builtin_amdgcn_mfma_f32_16x16x32_bf16(f[ks], a1[ks], acc1, 0, 0, 0);
        }
#pragma unroll
        for (int i = 0; i < 4; ++i) {
            float e0 = __builtin_amdgcn_exp2f(fmaf(acc0[i], s2, -s2));
            float e1 = __builtin_amdgcn_exp2f(fmaf(acc1[i], s2, -s2));
            float w0 = (float)((b0 >> i) & 1u);
            float w1 = (float)((b1 >> i) & 1u);
            sum0 += e0; pos0 = fmaf(w0, e0, pos0);
            sum1 += e1; pos1 = fmaf(w1, e1, pos1);
        }
    }
}

__global__ __launch_bounds__(THREADS, 4) void infonce_main(
    const short* __restrict__ Pb,   // [BATCH][DIM] bf16
    const short* __restrict__ Fp,   // packed F fragments (padded)
    const int*  __restrict__ mask,  // [BATCH][NUM_GO]
    const float* __restrict__ temp,
    float* __restrict__ rowsum,     // [BATCH] accum (zeroed)
    float* __restrict__ possum)     // [BATCH] accum (zeroed)
{
    __shared__ short flds[2][CHUNK_BYTES / 2];   // 32 KB (F double buffer)
    __shared__ unsigned char mbits[BM * 32];     // 8 KB  (4 chunks' mask, 1b/col)
    // total ~40 KB -> 2 blocks/CU (VGPR-capped)

    // bijective XCD-aware decode: blocks of the same GO segment -> same XCD
    const int bid = blockIdx.x;
    const int wid = (bid & 7) * (NBLK / 8) + (bid >> 3);
    const int by  = wid >> 4;       // GO segment 0..117
    const int bx  = wid & 15;       // row-block 0..15

    const int tid  = threadIdx.x;
    const int w    = tid >> 6;
    const int lane = tid & 63;
    const int lcol = lane & 15;
    const int lrow = lane >> 4;

    const int r0 = bx * BM + w * 32 + lcol;
    const int r1 = r0 + 16;

    const int c0 = by * CPS;
    const int nc = (c0 + CPS <= NCHUNKS) ? CPS : (NCHUNKS - c0);   // 4 or 1

    const float s2 = __expf(-temp[0]) * 1.44269504088896f;  // (1/exp(T))*log2e

    bf16x8 a0[4], a1[4];
#pragma unroll
    for (int ks = 0; ks < 4; ++ks) {
        a0[ks] = *(const bf16x8*)(Pb + (size_t)r0 * DIM + ks * 32 + lrow * 8);
        a1[ks] = *(const bf16x8*)(Pb + (size_t)r1 * DIM + ks * 32 + lrow * 8);
    }

    // F staging for chunk c0 (drained by the barrier below)
    {
        const char* gbase = (const char*)Fp + (size_t)c0 * CHUNK_BYTES;
        for (int off = w * 1024; off < CHUNK_BYTES; off += 8 * 1024)
            gload_lds16(gbase + off + lane * 16, (char*)flds[0] + off);
    }

    // ---- cooperative mask staging: ONE FULL WAVE-INSTRUCTION PER ROW ----
    // 64 lanes x 16B = 1024B contiguous per row visit (halves the 128B-line
    // boundary overfetch vs 512B visits; rows are 64B-misaligned when odd).
    // NON-TEMPORAL: zero-reuse stream, bypass L2/L3 allocation.
    // Bit-pack via nibble + shfl_xor(1): byte (lane>>1) of row covers cols
    // [lane*4, lane*4+8); u64 word i of a row = chunk c0+i, bit p = col p.
    {
        int col = c0 * 64 + lane * 4;
        if (col > NUM_GO - 4) col = NUM_GO - 4;      // tail-safe, dup reads ok
        const int* gp = mask + (size_t)(bx * BM + w * 32) * NUM_GO + col;

#pragma unroll
        for (int half = 0; half < 2; ++half) {
            i32x4 mv[16];
#pragma unroll
            for (int j = 0; j < 16; ++j)
                mv[j] = __builtin_nontemporal_load(
                    (const i32x4*)(gp + (size_t)(half * 16 + j) * NUM_GO));
#pragma unroll
            for (int j = 0; j < 16; ++j) {
                const int row = w * 32 + half * 16 + j;
                unsigned nib = (unsigned)(mv[j][0] | (mv[j][1] << 1) |
                                          (mv[j][2] << 2) | (mv[j][3] << 3));
                unsigned oth = (unsigned)__shfl_xor((int)nib, 1);
                if (!(lane & 1))
                    mbits[row * 32 + (lane >> 1)] =
                        (unsigned char)((nib | (oth << 4)) & 0xFF);
            }
        }
    }
    __syncthreads();   // mask bits + F chunk0 ready

    float sum0 = 0.f, pos0 = 0.f, sum1 = 0.f, pos1 = 0.f;
    const int rl0 = w * 32 + lcol;

    for (int i = 0; i < nc; ++i) {
        const int cur = i & 1, nxt = cur ^ 1;
        if (i + 1 < nc) {
            const char* gbase = (const char*)Fp + (size_t)(c0 + i + 1) * CHUNK_BYTES;
            for (int off = w * 1024; off < CHUNK_BYTES; off += 8 * 1024)
                gload_lds16(gbase + off + lane * 16, (char*)flds[nxt] + off);
        }
        __builtin_amdgcn_sched_barrier(0);   // keep prefetch issue above compute

        const unsigned long long wv0 =
            *(const unsigned long long*)(mbits + rl0 * 32 + i * 8);
        const unsigned long long wv1 =
            *(const unsigned long long*)(mbits + (rl0 + 16) * 32 + i * 8);

        if (c0 + i == NCHUNKS - 1)
            chunk_compute<3>(flds[cur], wv0, wv1, a0, a1, lane, lrow, s2,
                             sum0, pos0, sum1, pos1);
        else
            chunk_compute<4>(flds[cur], wv0, wv1, a0, a1, lane, lrow, s2,
                             sum0, pos0, sum1, pos1);
        __syncthreads();   // flds[nxt] staged; safe to overwrite flds[cur] next
    }

    // combine the 4 lrow replicas of each row's partials, 1 atomic per row
    sum0 += __shfl_xor(sum0, 16); sum0 += __shfl_xor(sum0, 32);
    pos0 += __shfl_xor(pos0, 16); pos0 += __shfl_xor(pos0, 32);
    sum1 += __shfl_xor(sum1, 16); sum1 += __shfl_xor(sum1, 32);
    pos1 += __shfl_xor(pos1, 16); pos1 += __shfl_xor(pos1, 32);
    if (lane < 16) {
        atomicAdd(&rowsum[r0], sum0);
        atomicAdd(&possum[r0], pos0);
        atomicAdd(&rowsum[r1], sum1);
        atomicAdd(&possum[r1], pos1);
    }
}

__global__ __launch_bounds__(256) void infonce_finalize(
    const float* __restrict__ rowsum, const float* __restrict__ possum,
    float* __restrict__ out)
{
    float acc = 0.f;
    for (int r = threadIdx.x; r < BATCH; r += 256) {
        float p = possum[r], sm = rowsum[r];
        if (p > 0.f) acc += -logf(p / sm + 1e-8f);   // has_pos <=> pos_sum > 0
    }
    __shared__ float red[4];
#pragma unroll
    for (int off = 32; off >= 1; off >>= 1) acc += __shfl_down(acc, off);
    if ((threadIdx.x & 63) == 0) red[threadIdx.x >> 6] = acc;
    __syncthreads();
    if (threadIdx.x == 0)
        out[0] = (red[0] + red[1] + red[2] + red[3]) * (1.0f / BATCH);
}

extern "C" void kernel_launch(void* const* d_in, const int* in_sizes, int n_in,
                              void* d_out, int out_size, void* d_ws, size_t ws_size,
                              hipStream_t stream) {
    const float* P    = (const float*)d_in[0];
    const float* F    = (const float*)d_in[1];
    const int*   mask = (const int*)d_in[2];
    const float* temp = (const float*)d_in[3];
    float* out = (float*)d_out;

    // ws: rowsum[4096] | possum[4096] | P_bf16 (1 MB) | F_packed (~7.7 MB)
    char* ws = (char*)d_ws;
    float* rowsum = (float*)ws;
    float* possum = (float*)(ws + 16384);
    short* Pb     = (short*)(ws + 32768);
    short* Fp     = (short*)(ws + 32768 + (size_t)BATCH * DIM * 2);

    hipMemsetAsync(rowsum, 0, 32768, stream);

    int nP4 = BATCH * DIM / 4;
    cvt_bf16<<<(nP4 + 255) / 256, 256, 0, stream>>>(P, Pb, nP4);
    cvt_F_packed<<<(NFRAGP + 255) / 256, 256, 0, stream>>>(F, Fp);

    infonce_main<<<NBLK, THREADS, 0, stream>>>(Pb, Fp, mask, temp,
                                               rowsum, possum);
    infonce_finalize<<<1, 256, 0, stream>>>(rowsum, possum, out);
}